// Round 5
// baseline (278.230 us; speedup 1.0000x reference)
//
#include <hip/hip_runtime.h>
#include <hip/hip_cooperative_groups.h>
#include <cmath>

namespace cg = cooperative_groups;

#define BINS 10
#define EDGE_TOP (1.0f + 1e-6f)
#define BLK 256
#define MAXJ 16          // max float4-groups/thread cached as codes in LDS
#define NSHADOW 32       // shadow histogram copies (contention /32)

// Classify via native v_exp_f32. Near-bin-boundary values recomputed with
// double-precision exp so the fp32 result matches numpy's fp32 exp.
// __expf rel err <= ~4e-7 -> disagreement band <= 8e-6 in g*10 space;
// margin 4e-5 is 5x safe. Proven R1-R4: absmax 7.8e-3 vs threshold 0.385.
__device__ __forceinline__ void ghm_classify_fast(float p, int& bin, bool& lt_top) {
    float ef  = __expf(-p);
    float g   = fabsf(ef - 1.0f);
    float g10 = g * 10.0f;
    int   b   = (int)g10;          // g >= 0, trunc == floor
    float fb  = (float)b;
    bool hazard = (g10 - fb < 4e-5f) || (fb + 1.0f - g10 < 4e-5f) ||
                  (fabsf(g - EDGE_TOP) < 4e-6f);
    if (hazard) {
        double ed = exp(-(double)p);
        float ef2 = (float)ed;     // ~correctly-rounded fp32 exp
        g   = fabsf(ef2 - 1.0f);
        g10 = g * 10.0f;
        b   = (int)g10;
    }
    bin    = (b < 9) ? b : 9;
    lt_top = (g < EDGE_TOP);
}

// One fused cooperative kernel:
//  phase 1: classify, 4-bit codes -> LDS (never touch HBM), per-thread packed
//           histogram (2 x u64, 12-bit fields: safe to 4095 elems/thread),
//           block-reduce -> device atomics into 32 shadow copies.
//  grid.sync()
//  phase 2: sum shadow copies, build 16-entry LDS weight table (reference
//           fp32 op order: (tot/counts[b])/n_nonempty; slot 15 = 0 sentinel),
//           re-read pred (LLC-warm) and write out = wtab[code]*pred.
__global__ __launch_bounds__(BLK, 8) void ghm_fused(
    const float* __restrict__ pred, const float* __restrict__ lw,
    unsigned int* __restrict__ shadow, float* __restrict__ out, int n)
{
    __shared__ unsigned short lds_codes[MAXJ * BLK];  // 8 KB
    __shared__ unsigned int sc[BINS + 1];
    __shared__ float wtab[16];

    const int tid = blockIdx.x * BLK + threadIdx.x;
    const int S   = gridDim.x * BLK;
    const int n4  = n >> 2;
    const float4* p4 = (const float4*)pred;
    const float4* w4 = (const float4*)lw;

    unsigned long long h0 = 0ull, h1 = 0ull;  // bins 0-4 / 5-9, 12-bit fields
    unsigned int vcnt = 0;

    // ---- phase 1 ----
    {
        int j = 0;
        int i = tid;
        if (i < n4) {
            float4 P0 = p4[i];
            float4 W0 = w4[i];
            while (true) {
                const int inext = i + S;
                const bool more = inext < n4;
                float4 P1, W1;
                if (more) { P1 = p4[inext]; W1 = w4[inext]; }  // prefetch

                float ps[4] = {P0.x, P0.y, P0.z, P0.w};
                float ws[4] = {W0.x, W0.y, W0.z, W0.w};
                unsigned int code = 0u;
#pragma unroll
                for (int k = 0; k < 4; ++k) {
                    bool valid = ws[k] > 0.0f;
                    vcnt += valid ? 1u : 0u;
                    int bin; bool lt;
                    ghm_classify_fast(ps[k], bin, lt);
                    bool ib = valid && lt;
                    bool hi = bin >= 5;
                    unsigned int sh = (unsigned int)((hi ? bin - 5 : bin) * 12);
                    unsigned long long inc = ib ? (1ull << sh) : 0ull;
                    h0 += hi ? 0ull : inc;
                    h1 += hi ? inc : 0ull;
                    code |= (ib ? (unsigned int)bin : 15u) << (k * 4);
                }
                if (j < MAXJ) lds_codes[j * BLK + threadIdx.x] = (unsigned short)code;
                ++j;
                if (!more) break;
                i = inext; P0 = P1; W0 = W1;
            }
        }
        // scalar tail (n % 4): counts only (phase 2 recomputes these)
        if (tid == 0) {
            for (int t = n4 << 2; t < n; ++t) {
                bool valid = lw[t] > 0.0f;
                vcnt += valid ? 1u : 0u;
                int bin; bool lt;
                ghm_classify_fast(pred[t], bin, lt);
                if (valid && lt) {
                    if (bin >= 5) h1 += 1ull << ((bin - 5) * 12);
                    else          h0 += 1ull << (bin * 12);
                }
            }
        }
    }

    // block reduce: wave shuffle -> LDS -> 11 atomics into this block's shadow copy
    if (threadIdx.x < BINS + 1) sc[threadIdx.x] = 0u;
    __syncthreads();
    {
        unsigned int vals[BINS + 1];
#pragma unroll
        for (int b = 0; b < 5; ++b) vals[b]     = (unsigned int)((h0 >> (12 * b)) & 4095ull);
#pragma unroll
        for (int b = 0; b < 5; ++b) vals[5 + b] = (unsigned int)((h1 >> (12 * b)) & 4095ull);
        vals[BINS] = vcnt;
#pragma unroll
        for (int b = 0; b <= BINS; ++b) {
            unsigned int v = vals[b];
#pragma unroll
            for (int off = 32; off > 0; off >>= 1)
                v += __shfl_down(v, off, 64);
            if ((threadIdx.x & 63) == 0) atomicAdd(&sc[b], v);
        }
    }
    __syncthreads();
    if (threadIdx.x < BINS + 1)
        atomicAdd(&shadow[(blockIdx.x & (NSHADOW - 1)) * 16 + threadIdx.x],
                  sc[threadIdx.x]);

    cg::this_grid().sync();

    // ---- phase 2: weights ----
    {
        const int lane = threadIdx.x & 63;
        unsigned int cv = 0u;
        if (lane < BINS + 1) {
#pragma unroll
            for (int c = 0; c < NSHADOW; ++c)
                cv += __hip_atomic_load(&shadow[c * 16 + lane],
                                        __ATOMIC_RELAXED, __HIP_MEMORY_SCOPE_AGENT);
        }
        float totf = fmaxf((float)__shfl((int)cv, 10, 64), 1.0f);
        unsigned long long nem = __ballot(lane < 10 && cv > 0u);
        int nne = __popcll(nem);
        float nf = fmaxf((float)nne, 1.0f);
        float wfl = 0.0f;
        if (lane < 10 && cv > 0u) {
            wfl = totf / (float)cv;        // tot / counts[b]
            if (nne > 0) wfl = wfl / nf;   // / n_nonempty (reference op order)
        }
        if (threadIdx.x < 16) wtab[threadIdx.x] = wfl;  // lanes 10..15 -> 0.0
    }
    __syncthreads();

    // ---- phase 2: output ----
    {
        int j = 0;
        int i = tid;
        if (i < n4) {
            float4 P0 = p4[i];
            while (true) {
                const int inext = i + S;
                const bool more = inext < n4;
                float4 P1;
                if (more) P1 = p4[inext];  // prefetch

                unsigned int code;
                if (j < MAXJ) {
                    code = lds_codes[j * BLK + threadIdx.x];
                } else {  // LDS overflow fallback (not hit for this shape)
                    float4 W = w4[i];
                    float ws_[4] = {W.x, W.y, W.z, W.w};
                    float ps_[4] = {P0.x, P0.y, P0.z, P0.w};
                    code = 0u;
#pragma unroll
                    for (int k = 0; k < 4; ++k) {
                        int bin; bool lt;
                        ghm_classify_fast(ps_[k], bin, lt);
                        bool ib = (ws_[k] > 0.0f) && lt;
                        code |= (ib ? (unsigned int)bin : 15u) << (k * 4);
                    }
                }
                float ps[4] = {P0.x, P0.y, P0.z, P0.w};
                float os[4];
#pragma unroll
                for (int k = 0; k < 4; ++k) {
                    unsigned int idx = (code >> (k * 4)) & 15u;
                    os[k] = wtab[idx] * ps[k];   // <=16 words: broadcast, no conflicts
                }
                float4 O;
                O.x = os[0]; O.y = os[1]; O.z = os[2]; O.w = os[3];
                ((float4*)out)[i] = O;
                ++j;
                if (!more) break;
                i = inext; P0 = P1;
            }
        }
        // scalar tail: recompute directly
        if (tid == 0) {
            for (int t = n4 << 2; t < n; ++t) {
                int bin; bool lt;
                ghm_classify_fast(pred[t], bin, lt);
                bool ib = (lw[t] > 0.0f) && lt;
                out[t] = wtab[ib ? bin : 15] * pred[t];
            }
        }
    }
}

extern "C" void kernel_launch(void* const* d_in, const int* in_sizes, int n_in,
                              void* d_out, int out_size, void* d_ws, size_t ws_size,
                              hipStream_t stream)
{
    const float* pred = (const float*)d_in[0];
    // d_in[1] = target, unused by the math
    const float* lw   = (const float*)d_in[2];
    float* out        = (float*)d_out;
    const int n       = in_sizes[0];

    unsigned int* shadow = (unsigned int*)d_ws;  // NSHADOW x 16 u32 = 2 KB

    // ws is poisoned 0xAA before every call — zero the shadow counters on-stream.
    hipMemsetAsync(d_ws, 0, NSHADOW * 16 * sizeof(unsigned int), stream);

    // Cooperative grid: guaranteed co-resident (query occupancy every call —
    // pure host query, capture-safe, deterministic).
    int dev = 0;
    hipGetDevice(&dev);
    int numCU = 0;
    hipDeviceGetAttribute(&numCU, hipDeviceAttributeMultiprocessorCount, dev);
    int maxB = 0;
    hipOccupancyMaxActiveBlocksPerMultiprocessor(&maxB, (const void*)ghm_fused, BLK, 0);
    long long G = (long long)maxB * (long long)numCU;
    if (G > 2048) G = 2048;           // 8 elems-> ~32/thread, LDS codes fit MAXJ
    long long n4 = (long long)(n >> 2);
    long long needed = (n4 > 0) ? (n4 + BLK - 1) / BLK : 1;
    if (G > needed) G = needed;
    if (G < 1) G = 1;

    void* args[] = { (void*)&pred, (void*)&lw, (void*)&shadow, (void*)&out, (void*)&n };
    hipLaunchCooperativeKernel((const void*)ghm_fused, dim3((unsigned int)G),
                               dim3(BLK), args, 0, stream);
}